// Round 3
// baseline (4840.060 us; speedup 1.0000x reference)
//
#include <hip/hip_runtime.h>
#include <math.h>

// B=512, D_MODEL=1024, D_INNER=2048, DT_RANK=64, D_STATE=64, NBC=192,
// C_OUT=64, PRED_LEN=96.
// Persistent kernel: 512 blocks x 512 threads, >=2 blocks/CU co-resident
// (28KB LDS, VGPR capped via __launch_bounds__(512,4)).
// 16 groups (32 batch rows) x 32 tiles (64 cols each).
// Cross-block traffic via device-scope atomics at MALL; group barriers via
// atomic counters. Zeroing/dout writes load-balanced across all tiles.

#define AGENT __HIP_MEMORY_SCOPE_AGENT

__device__ __forceinline__ float sigf(float v){
  return __builtin_amdgcn_rcpf(1.f + __expf(-v));
}

// ---------------- setup kernels ----------------

__global__ __launch_bounds__(256) void k_ctx(
    const float* __restrict__ ctxin, const float* __restrict__ w_in,
    const float* __restrict__ b_in, float* __restrict__ ctx_xz){
  int tid = threadIdx.x;
  int j = blockIdx.x*256 + tid;
  int b0 = blockIdx.y*16;
  const float* cp = ctxin + (size_t)b0*1024;
  float acc[16];
#pragma unroll
  for (int r=0;r<16;r++) acc[r]=0.f;
  for (int k=0;k<1024;k+=4){
    float w0 = w_in[(size_t)(k+0)*4096 + j];
    float w1 = w_in[(size_t)(k+1)*4096 + j];
    float w2 = w_in[(size_t)(k+2)*4096 + j];
    float w3 = w_in[(size_t)(k+3)*4096 + j];
#pragma unroll
    for (int r=0;r<16;r++){
      acc[r] += cp[r*1024+k]*w0 + cp[r*1024+k+1]*w1
              + cp[r*1024+k+2]*w2 + cp[r*1024+k+3]*w3;
    }
  }
  float bj = b_in[j];
#pragma unroll
  for (int r=0;r<16;r++) ctx_xz[(size_t)(b0+r)*4096 + j] = acc[r] + bj;
}

__global__ __launch_bounds__(256) void k_wop(
    const float* __restrict__ w_out, const float* __restrict__ w_proj,
    const float* __restrict__ b_out, const float* __restrict__ b_proj,
    float* __restrict__ W_op, float* __restrict__ b_op){
  int g = blockIdx.x, tid = threadIdx.x;
  if (g == 512){
    if (tid < 64){
      float s = b_proj[tid];
      for (int k=0;k<1024;k++) s += b_out[k]*w_proj[k*64+tid];
      b_op[tid] = s;
    }
    return;
  }
  int idx = g*256 + tid;
  int c = idx>>6, o = idx&63;
  float s = 0.f;
  const float* wr = w_out + (size_t)c*1024;
  for (int k=0;k<1024;k++) s += wr[k]*w_proj[k*64+o];
  W_op[idx] = s;
}

__global__ __launch_bounds__(256) void k_cvec(
    const float* __restrict__ b_op, const float* __restrict__ w_in2,
    float* __restrict__ cvec){
  int j = blockIdx.x*256 + threadIdx.x;
  float s = 0.f;
  for (int o=0;o<64;o++) s += b_op[o]*w_in2[(size_t)o*4096 + j];
  cvec[j] = s;
}

__global__ void k_zero(float* __restrict__ p, int n){
  int i = blockIdx.x*256 + threadIdx.x;
  if (i < n) p[i] = 0.f;
}

// ---------------- persistent step kernel ----------------

__device__ __forceinline__ void gbar(int* flag, int target){
  __syncthreads();             // drains vmcnt(0): all atomics of this block acked
  if (threadIdx.x == 0){
    __hip_atomic_fetch_add(flag, 1, __ATOMIC_RELEASE, AGENT);
    while (__hip_atomic_load(flag, __ATOMIC_RELAXED, AGENT) < target)
      __builtin_amdgcn_s_sleep(1);
  }
  __syncthreads();
}

__global__ __launch_bounds__(512,4) void k_steps(
    const float* __restrict__ ctx_xz, const float* __restrict__ cvec,
    const float* __restrict__ w_in2,  const float* __restrict__ conv_w,
    const float* __restrict__ conv_b, const float* __restrict__ w_x,
    const float* __restrict__ w_dt,   const float* __restrict__ b_dt,
    const float* __restrict__ D_skip, const float* __restrict__ W_op,
    const float* __restrict__ b_op,   const float* __restrict__ initial,
    float* __restrict__ xd0, float* __restrict__ xd1,
    float* __restrict__ pa0, float* __restrict__ pa1,
    int* __restrict__ flags, float* __restrict__ dout)
{
  const int tid  = threadIdx.x;
  const int bt   = blockIdx.x & 15;   // group: 32 batch rows
  const int tile = blockIdx.x >> 4;   // 0..31: 64 cols
  const int lane = tid & 63;
  const int rq   = tid >> 6;          // 0..7: rows rq*4..rq*4+3
  const int r0   = bt * 32;
  const int rb4  = rq * 4;
  const int jx   = tile*64 + lane;    // x / c column (0..2047)
  const int jz   = 2048 + jx;

  __shared__ float predT[64][36];   // [o][row] (stride 36 keeps float4 alignment)
  __shared__ float xT[64][36];      // phase A: x [col][row]; phase C: xdbc_dt [o][row]
  __shared__ float yT[64][36];      // [col][row]
  __shared__ float bcL[32];

  const float cw  = conv_w[jx*4+3];
  const float cb  = conv_b[jx];
  const float cvx = cvec[jx];
  const float cvz = cvec[jz];
  const float bdt = b_dt[jx];
  const float dsk = D_skip[jx];
  const float bop = b_op[lane];
  float ctxv[4], ctzv[4];
#pragma unroll
  for (int r=0;r<4;r++){
    ctxv[r] = ctx_xz[(size_t)(r0+rb4+r)*4096 + jx];
    ctzv[r] = ctx_xz[(size_t)(r0+rb4+r)*4096 + jz];
  }
  int* flag = flags + bt*32;

  for (int t=0; t<96; t++){
    const float* pin = (t&1) ? pa1 : pa0;
    float*       pout= (t&1) ? pa0 : pa1;
    float*       xdc = (t&1) ? xd1 : xd0;
    float*       xdn = (t&1) ? xd0 : xd1;

    // ---- Phase A ----
    {
      float p0,p1,p2,p3;
      if (t == 0){
        p0 = initial[(size_t)(r0+rb4+0)*64 + lane];
        p1 = initial[(size_t)(r0+rb4+1)*64 + lane];
        p2 = initial[(size_t)(r0+rb4+2)*64 + lane];
        p3 = initial[(size_t)(r0+rb4+3)*64 + lane];
      } else {
        p0 = __hip_atomic_load(&pin[(size_t)(r0+rb4+0)*64 + lane], __ATOMIC_RELAXED, AGENT);
        p1 = __hip_atomic_load(&pin[(size_t)(r0+rb4+1)*64 + lane], __ATOMIC_RELAXED, AGENT);
        p2 = __hip_atomic_load(&pin[(size_t)(r0+rb4+2)*64 + lane], __ATOMIC_RELAXED, AGENT);
        p3 = __hip_atomic_load(&pin[(size_t)(r0+rb4+3)*64 + lane], __ATOMIC_RELAXED, AGENT);
      }
      *(float4*)&predT[lane][rb4] = make_float4(p0,p1,p2,p3);
    }
    // distributed zero of pout (64 elems/tile), before any pred atomics (gbar1 orders)
    if (tid < 64)
      __hip_atomic_store(&pout[(size_t)r0*64 + tile*64 + tid], 0.f, __ATOMIC_RELAXED, AGENT);
    __syncthreads();
    // distributed dout write for step t-1: this tile handles batch row (r0+tile)
    if (t > 0 && tid < 64)
      dout[((size_t)(r0+tile)*96 + (t-1))*64 + tid] = predT[tid][tile] + bop;

    // GEMM1 (x half): acc = ctx + pred @ w_in2[:, jx]
    float acc[4];
#pragma unroll
    for (int r=0;r<4;r++) acc[r] = ctxv[r] + (t ? cvx : 0.f);
#pragma unroll 2
    for (int o=0;o<64;o++){
      float w = w_in2[(size_t)o*4096 + jx];
      float4 p = *(const float4*)&predT[o][rb4];
      acc[0] += p.x*w; acc[1] += p.y*w; acc[2] += p.z*w; acc[3] += p.w*w;
    }
    float xv[4];
#pragma unroll
    for (int r=0;r<4;r++){
      float v = acc[r]*cw + cb;
      xv[r] = v * sigf(v);
    }
    *(float4*)&xT[lane][rb4] = make_float4(xv[0],xv[1],xv[2],xv[3]);
    __syncthreads();

    // xdbc partials over this tile's K=64 cols
    {
      float f0[4]={0,0,0,0}, f1[4]={0,0,0,0}, f2[4]={0,0,0,0};
#pragma unroll 4
      for (int k=0;k<64;k++){
        const float* wxp = &w_x[(size_t)(tile*64+k)*192 + lane];
        float w0 = wxp[0], w1 = wxp[64], w2 = wxp[128];
        float4 xk = *(const float4*)&xT[k][rb4];
        f0[0]+=xk.x*w0; f0[1]+=xk.y*w0; f0[2]+=xk.z*w0; f0[3]+=xk.w*w0;
        f1[0]+=xk.x*w1; f1[1]+=xk.y*w1; f1[2]+=xk.z*w1; f1[3]+=xk.w*w1;
        f2[0]+=xk.x*w2; f2[1]+=xk.y*w2; f2[2]+=xk.z*w2; f2[3]+=xk.w*w2;
      }
#pragma unroll
      for (int r=0;r<4;r++){
        size_t base = (size_t)(r0+rb4+r)*192 + lane;
        atomicAdd(&xdc[base      ], f0[r]);
        atomicAdd(&xdc[base +  64], f1[r]);
        atomicAdd(&xdc[base + 128], f2[r]);
      }
    }

    // z-half GEMM moved here: independent of xdbc -> hides atomic drain
    float zacc[4];
#pragma unroll
    for (int r=0;r<4;r++) zacc[r] = ctzv[r] + (t ? cvz : 0.f);
#pragma unroll 2
    for (int o=0;o<64;o++){
      float w = w_in2[(size_t)o*4096 + jz];
      float4 p = *(const float4*)&predT[o][rb4];
      zacc[0] += p.x*w; zacc[1] += p.y*w; zacc[2] += p.z*w; zacc[3] += p.w*w;
    }
    // distributed zero of next step's xdbc buffer (192 elems/tile)
    if (tid < 192)
      __hip_atomic_store(&xdn[(size_t)r0*192 + tile*192 + tid], 0.f, __ATOMIC_RELAXED, AGENT);

    gbar(flag, 32*(2*t+1));

    // ---- Phase C ----
    {
      float d0 = __hip_atomic_load(&xdc[(size_t)(r0+rb4+0)*192 + lane], __ATOMIC_RELAXED, AGENT);
      float d1 = __hip_atomic_load(&xdc[(size_t)(r0+rb4+1)*192 + lane], __ATOMIC_RELAXED, AGENT);
      float d2 = __hip_atomic_load(&xdc[(size_t)(r0+rb4+2)*192 + lane], __ATOMIC_RELAXED, AGENT);
      float d3 = __hip_atomic_load(&xdc[(size_t)(r0+rb4+3)*192 + lane], __ATOMIC_RELAXED, AGENT);
      *(float4*)&xT[lane][rb4] = make_float4(d0,d1,d2,d3);   // xdbc_dt [o][row]
      // bc: per-row dot of B,C segments
#pragma unroll
      for (int r=0;r<4;r++){
        size_t row = (size_t)(r0+rb4+r)*192;
        float Bv = __hip_atomic_load(&xdc[row +  64 + lane], __ATOMIC_RELAXED, AGENT);
        float Cv = __hip_atomic_load(&xdc[row + 128 + lane], __ATOMIC_RELAXED, AGENT);
        float p = Bv*Cv;
#pragma unroll
        for (int s=1; s<64; s<<=1) p += __shfl_xor(p, s, 64);
        if (lane == 0) bcL[rb4+r] = p;
      }
    }
    __syncthreads();

    // dt GEMM (K=64) + y
    float dacc[4] = {0,0,0,0};
#pragma unroll 2
    for (int o=0;o<64;o++){
      float w = w_dt[(size_t)o*2048 + jx];
      float4 x4 = *(const float4*)&xT[o][rb4];
      dacc[0] += x4.x*w; dacc[1] += x4.y*w; dacc[2] += x4.z*w; dacc[3] += x4.w*w;
    }
    float yv[4];
#pragma unroll
    for (int r=0;r<4;r++){
      float zs = zacc[r]*sigf(zacc[r]);
      float v = dacc[r] + bdt;
      float dt = (v > 15.f) ? v : __logf(1.f + __expf(v));
      yv[r] = (dt*bcL[rb4+r] + dsk) * xv[r] * zs;
    }
    *(float4*)&yT[lane][rb4] = make_float4(yv[0],yv[1],yv[2],yv[3]);
    __syncthreads();

    // pred partials over this tile's K=64
    {
      float pacc[4]={0,0,0,0};
#pragma unroll 4
      for (int k=0;k<64;k++){
        float w = W_op[(size_t)(tile*64+k)*64 + lane];
        float4 y4 = *(const float4*)&yT[k][rb4];
        pacc[0]+=y4.x*w; pacc[1]+=y4.y*w; pacc[2]+=y4.z*w; pacc[3]+=y4.w*w;
      }
#pragma unroll
      for (int r=0;r<4;r++)
        atomicAdd(&pout[(size_t)(r0+rb4+r)*64 + lane], pacc[r]);
    }
    gbar(flag, 32*(2*t+2));
  }

  // final pred (t=95, odd -> pa0); tile handles row r0+tile
  if (tid < 64){
    float v = __hip_atomic_load(&pa0[(size_t)(r0+tile)*64 + tid], __ATOMIC_RELAXED, AGENT);
    dout[((size_t)(r0+tile)*96 + 95)*64 + tid] = v + bop;
  }
}

// ---------------- launch ----------------

extern "C" void kernel_launch(void* const* d_in, const int* in_sizes, int n_in,
                              void* d_out, int out_size, void* d_ws, size_t ws_size,
                              hipStream_t stream)
{
  const float* context = (const float*)d_in[0];
  const float* initial = (const float*)d_in[1];
  const float* w_in    = (const float*)d_in[2];
  const float* b_in    = (const float*)d_in[3];
  const float* conv_w  = (const float*)d_in[4];
  const float* conv_b  = (const float*)d_in[5];
  const float* w_x     = (const float*)d_in[6];
  const float* w_dt    = (const float*)d_in[7];
  const float* b_dt    = (const float*)d_in[8];
  // d_in[9] = A_log (unused: L=1, h0=0)
  const float* D_skip  = (const float*)d_in[10];
  const float* w_out   = (const float*)d_in[11];
  const float* b_out   = (const float*)d_in[12];
  const float* w_proj  = (const float*)d_in[13];
  const float* b_proj  = (const float*)d_in[14];

  float* ws = (float*)d_ws;
  float* ctx_xz = ws;                    // 2,097,152
  float* cvec   = ctx_xz + 2097152;      // 4,096
  float* W_op   = cvec + 4096;           // 131,072
  float* b_op   = W_op + 131072;         // 128
  float* xd0    = b_op + 128;            // 98,304
  int*   flags  = (int*)(xd0 + 98304);   // 512 ints
  float* xd1    = xd0 + 98304 + 512;     // 98,304
  float* pa0    = xd1 + 98304;           // 32,768
  float* pa1    = pa0 + 32768;           // 32,768
  float* dout   = (float*)d_out;

  const float* w_in2 = w_in + (size_t)1024*4096;

  k_wop <<<dim3(513),   256, 0, stream>>>(w_out, w_proj, b_out, b_proj, W_op, b_op);
  k_cvec<<<dim3(16),    256, 0, stream>>>(b_op, w_in2, cvec);
  k_ctx <<<dim3(16,32), 256, 0, stream>>>(context, w_in, b_in, ctx_xz);
  k_zero<<<dim3(387),   256, 0, stream>>>(xd0, 98304 + 512);  // xd0 + flags

  k_steps<<<dim3(512), 512, 0, stream>>>(ctx_xz, cvec, w_in2, conv_w, conv_b,
                                         w_x, w_dt, b_dt, D_skip, W_op, b_op,
                                         initial, xd0, xd1, pa0, pa1,
                                         flags, dout);
}